// Round 3
// baseline (338.868 us; speedup 1.0000x reference)
//
#include <hip/hip_runtime.h>
#include <math.h>

#define T_LEN 2048
#define BSZ 2
#define EMB 1024
#define NHEAD 16
#define HDIM 64
#define QK_LD 2048   // q,k packed [T*B, 2E]

typedef __attribute__((ext_vector_type(8))) short short8v;   // 8 bf16 (4 VGPRs)
typedef __attribute__((ext_vector_type(4))) float floatx4;   // MFMA C/D

__device__ __forceinline__ short f2bf(float f) {
    unsigned u = __float_as_uint(f);
    u += 0x7fffu + ((u >> 16) & 1u);   // RNE
    return (short)(u >> 16);
}

// async global->LDS, 16B per lane; LDS dest is wave-uniform base + lane*16.
__device__ __forceinline__ void async16(const short* g, short* l) {
    __builtin_amdgcn_global_load_lds(
        (const __attribute__((address_space(1))) void*)g,
        (__attribute__((address_space(3))) void*)l, 16, 0, 0);
}

// ---------------------------------------------------------------------------
__global__ __launch_bounds__(256) void f32_to_bf16_k(const float* __restrict__ src,
                                                     short* __restrict__ dst, int n) {
    int i = (blockIdx.x * 256 + threadIdx.x) * 4;
    if (i >= n) return;
    float4 v = *(const float4*)(src + i);
    short4 o = make_short4(f2bf(v.x), f2bf(v.y), f2bf(v.z), f2bf(v.w));
    *(short4*)(dst + i) = o;
}

// ---------------------------------------------------------------------------
// C = A[M,K]*B[N,K]^T + bias; cols < scale_cols get *0.125 (q scale).
// bf16 MFMA 16x16x32, 128x128 tile, BK=32, 4 waves.
// Staging: __builtin_amdgcn_global_load_lds width 16 (m97 structure).
//   LDS dest is LINEAR (wave-uniform base + lane*16); the read-side XOR
//   swizzle (chunk q ^ ((row>>1)&3), 2-way-free banks) is an involution,
//   so it is applied to the GLOBAL source chunk index instead (rule 21:
//   linear dest + inverse-swizzled source + swizzled read).
// GRID IS (mtile, ntile): linear%8 = mtile%8, so each XCD keeps its 4
// A-slabs resident in L2. If vTout != 0, cols >= 2*EMB are written
// TRANSPOSED to vT[b][e][t].
// ---------------------------------------------------------------------------
__global__ __launch_bounds__(256) void gemm_bf16(const short* __restrict__ A,
        const short* __restrict__ B, const float* __restrict__ bias,
        void* __restrict__ Cout, short* __restrict__ vTout,
        int M, int N, int K, int scale_cols, int out_bf16, int ldC) {
    __shared__ short As[128][32];
    __shared__ short Bs[128][32];
    const int tid = threadIdx.x;
    const int m0 = blockIdx.x * 128, n0 = blockIdx.y * 128;   // x=mtile (XCD locality)
    const int lane = tid & 63, w = tid >> 6;
    const int q = lane >> 4, r = lane & 15;
    const int wr = w >> 1, wc = w & 1;

    // Staging geometry: wave w stages 16-row chunks {w, w+4} of both tiles.
    // Lane l -> row chunk*16 + (l>>2), 16B position (l&3) within the 64B row.
    const int srow = lane >> 2;                  // 0..15 within chunk
    const int spos = lane & 3;                   // 16B slot within row
    const int rowL = w * 16 + srow;              // chunk w   (rows 0..63)
    const int rowH = 64 + rowL;                  // chunk w+4 (rows 64..127)
    const int csrc = spos ^ ((rowL >> 1) & 3);   // f(rowH) == f(rowL)
    const short* gA0 = A + (size_t)(m0 + rowL) * K + csrc * 8;
    const short* gA1 = A + (size_t)(m0 + rowH) * K + csrc * 8;
    const short* gB0 = B + (size_t)(n0 + rowL) * K + csrc * 8;
    const short* gB1 = B + (size_t)(n0 + rowH) * K + csrc * 8;
    short* lA0 = &As[w * 16][0];                 // wave-uniform LDS bases
    short* lA1 = &As[64 + w * 16][0];
    short* lB0 = &Bs[w * 16][0];
    short* lB1 = &Bs[64 + w * 16][0];

    floatx4 acc[4][4];
    #pragma unroll
    for (int a = 0; a < 4; ++a)
        #pragma unroll
        for (int b2 = 0; b2 < 4; ++b2)
            #pragma unroll
            for (int e = 0; e < 4; ++e) acc[a][b2][e] = 0.f;

    for (int k0 = 0; k0 < K; k0 += 32) {
        __syncthreads();                 // previous iter's ds_reads complete
        async16(gA0 + k0, lA0);
        async16(gA1 + k0, lA1);
        async16(gB0 + k0, lB0);
        async16(gB1 + k0, lB1);
        __syncthreads();                 // vmcnt(0) drain + barrier
        short8v af[4], bfr[4];
        #pragma unroll
        for (int mb = 0; mb < 4; ++mb) {
            int row = wr * 64 + mb * 16 + r;
            af[mb] = *(const short8v*)&As[row][(q ^ ((row >> 1) & 3)) * 8];
        }
        #pragma unroll
        for (int nb = 0; nb < 4; ++nb) {
            int row = wc * 64 + nb * 16 + r;
            bfr[nb] = *(const short8v*)&Bs[row][(q ^ ((row >> 1) & 3)) * 8];
        }
        #pragma unroll
        for (int mb = 0; mb < 4; ++mb)
            #pragma unroll
            for (int nb = 0; nb < 4; ++nb)
                acc[mb][nb] = __builtin_amdgcn_mfma_f32_16x16x32_bf16(af[mb], bfr[nb], acc[mb][nb], 0, 0, 0);
    }

    #pragma unroll
    for (int nb = 0; nb < 4; ++nb) {
        const int col = n0 + wc * 64 + nb * 16 + r;
        const float bi = bias[col];
        const float sc = (col < scale_cols) ? 0.125f : 1.0f;
        if (vTout && col >= 2 * EMB) {
            const int e = col - 2 * EMB;
            #pragma unroll
            for (int mb = 0; mb < 4; ++mb) {
                const int base = m0 + wr * 64 + mb * 16 + q * 4;   // multiple of 4
                float v0 = acc[mb][nb][0] + bi, v1 = acc[mb][nb][1] + bi;
                float v2 = acc[mb][nb][2] + bi, v3 = acc[mb][nb][3] + bi;
                // rows (t*2+b): i=0,2 -> b=0 t,t+1 ; i=1,3 -> b=1 t,t+1
                unsigned lo = (unsigned short)f2bf(v0) | ((unsigned)(unsigned short)f2bf(v2) << 16);
                unsigned hi = (unsigned short)f2bf(v1) | ((unsigned)(unsigned short)f2bf(v3) << 16);
                *(unsigned*)&vTout[(size_t)e * T_LEN + (base >> 1)]         = lo;
                *(unsigned*)&vTout[((size_t)EMB + e) * T_LEN + (base >> 1)] = hi;
            }
        } else {
            #pragma unroll
            for (int mb = 0; mb < 4; ++mb)
                #pragma unroll
                for (int i = 0; i < 4; ++i) {
                    const int rowg = m0 + wr * 64 + mb * 16 + q * 4 + i;
                    const float v = (acc[mb][nb][i] + bi) * sc;
                    if (out_bf16) ((short*)Cout)[(size_t)rowg * ldC + col] = f2bf(v);
                    else          ((float*)Cout)[(size_t)rowg * ldC + col] = v;
                }
        }
    }
}

// ---------------------------------------------------------------------------
// Flash causal attention. ONE t-tile per block (grid 32 bh x 32 tt), big
// tiles dispatched first (tt = 31 - blockIdx.y) so the tail is short work.
// linear%8 = bh%8 -> each XCD hosts 4 bh values, K/V working set 2 MB fits
// per-XCD L2. 2 s-tiles per staging round via global_load_lds width 16
// (linear LDS dest + inverse-swizzled global source; read swizzle is the
// same involution). P double-buffered, no online max.
// ---------------------------------------------------------------------------
__global__ __launch_bounds__(256) void flash_fwd(const short* __restrict__ qk,
        const short* __restrict__ vT, short* __restrict__ ctx,
        float* __restrict__ Lr) {
    __shared__ short Ks[128][64];       // 2 s-tiles of K
    __shared__ short Vt[64][128];       // V^T: [d][2 s-tiles]
    __shared__ short Ps[2][64][64];     // P dbuf; Ps[0] doubles as Q staging
    __shared__ float Lred[4][64];
    const int tid = threadIdx.x;
    const int bh = blockIdx.x;          // XCD locality: linear%8 = bh%8
    const int tt = 31 - blockIdx.y;     // big tiles first
    const int t0 = tt << 6;
    const int b = bh >> 4, h = bh & 15;
    const int lane = tid & 63, w = tid >> 6;
    const int q = lane >> 4, r = lane & 15;
    const int RS = BSZ * QK_LD;

    const short* qbase = qk + (size_t)b * QK_LD + h * HDIM;
    const short* kbase = qbase + EMB;
    const short* vbase = vT + ((size_t)b * EMB + h * HDIM) * T_LEN;

    // async staging geometry (paired rounds):
    // K: Ks[128][64]. issue (w,j): rows w*32+j*8; lane -> row +(l>>3), chunk l&7.
    //    j*8 doesn't change row&7 -> source chunk swizzle is j-invariant.
    const int krow0 = w * 32 + (lane >> 3);
    const short* kg = kbase + (size_t)krow0 * RS + ((lane & 7) ^ (krow0 & 7)) * 8;
    // V: Vt[64][128]. issue (w,j): rows w*16+j*4; lane -> row +(l>>4), chunk l&15.
    const int vrow0 = w * 16 + (lane >> 4);
    const short* vg[4];
    #pragma unroll
    for (int j = 0; j < 4; ++j) {
        const int vr = vrow0 + j * 4;
        const int gc = ((lane & 15) & 8) | (((lane & 15) & 7) ^ (vr & 7));
        vg[j] = vbase + (size_t)vr * T_LEN + gc * 8;
    }

    {   // stage Q into Ps[0]
        const int sr = tid >> 3, c8 = tid & 7;
        *(int4*)&Ps[0][sr][(c8 ^ (sr & 7)) * 8] =
            *(const int4*)(qbase + (size_t)(t0 + sr) * RS + c8 * 8);
        *(int4*)&Ps[0][sr + 32][(c8 ^ ((sr + 32) & 7)) * 8] =
            *(const int4*)(qbase + (size_t)(t0 + sr + 32) * RS + c8 * 8);
    }
    __syncthreads();
    short8v qf[4][2];
    #pragma unroll
    for (int mb = 0; mb < 4; ++mb)
        #pragma unroll
        for (int ks = 0; ks < 2; ++ks) {
            int row = mb * 16 + r;
            qf[mb][ks] = *(const short8v*)&Ps[0][row][((ks * 4 + q) ^ (row & 7)) * 8];
        }

    float l_part[4][4];
    floatx4 o[4];
    #pragma unroll
    for (int mb = 0; mb < 4; ++mb)
        #pragma unroll
        for (int i = 0; i < 4; ++i) l_part[mb][i] = 0.f;
    #pragma unroll
    for (int nb = 0; nb < 4; ++nb)
        #pragma unroll
        for (int e = 0; e < 4; ++e) o[nb][e] = 0.f;

    const int ntiles = tt + 1;
    int s2 = 0;
    for (; s2 + 2 <= ntiles; s2 += 2) {   // paired rounds: 128 s per stage
        __syncthreads();                  // prior PV reads of Ks/Vt done
        {   // async K: 4 issues x 8 rows; V: 4 issues x 4 rows
            const short* kgr = kg + (size_t)(s2 * 64) * RS;
            #pragma unroll
            for (int j = 0; j < 4; ++j)
                async16(kgr + (size_t)(j * 8) * RS, &Ks[w * 32 + j * 8][0]);
            #pragma unroll
            for (int j = 0; j < 4; ++j)
                async16(vg[j] + s2 * 64, &Vt[w * 16 + j * 4][0]);
        }
        __syncthreads();                  // vmcnt(0) drain + barrier
        #pragma unroll
        for (int t2 = 0; t2 < 2; ++t2) {   // QK + P for both tiles
            floatx4 sf[4];
            #pragma unroll
            for (int mb = 0; mb < 4; ++mb)
                #pragma unroll
                for (int e = 0; e < 4; ++e) sf[mb][e] = 0.f;
            #pragma unroll
            for (int ks = 0; ks < 2; ++ks) {
                const int krow = t2 * 64 + w * 16 + r;
                short8v kf = *(const short8v*)&Ks[krow][((ks * 4 + q) ^ (krow & 7)) * 8];
                #pragma unroll
                for (int mb = 0; mb < 4; ++mb)
                    sf[mb] = __builtin_amdgcn_mfma_f32_16x16x32_bf16(qf[mb][ks], kf, sf[mb], 0, 0, 0);
            }
            const bool diag = (s2 + t2 == tt);
            #pragma unroll
            for (int mb = 0; mb < 4; ++mb)
                #pragma unroll
                for (int i = 0; i < 4; ++i) {
                    const int rl = mb * 16 + q * 4 + i;
                    float p = (diag && (w * 16 + r > rl)) ? 0.f : __expf(sf[mb][i]);
                    l_part[mb][i] += p;
                    const int c = (w * 2 + (r >> 3)) ^ (rl & 7);
                    Ps[t2][rl][c * 8 + (r & 7)] = f2bf(p);
                }
        }
        __syncthreads();
        #pragma unroll
        for (int ks = 0; ks < 2; ++ks) {   // PV both s-halves
            const int prow = w * 16 + r;
            const int pcp = ((ks * 4 + q) ^ (prow & 7)) * 8;
            short8v pfA = *(const short8v*)&Ps[0][prow][pcp];
            short8v pfB = *(const short8v*)&Ps[1][prow][pcp];
            #pragma unroll
            for (int nb = 0; nb < 4; ++nb) {
                const int vrow = nb * 16 + r;
                const int pcv = (ks * 4 + q) ^ (vrow & 7);
                short8v vfA = *(const short8v*)&Vt[vrow][pcv * 8];
                short8v vfB = *(const short8v*)&Vt[vrow][(8 | pcv) * 8];
                o[nb] = __builtin_amdgcn_mfma_f32_16x16x32_bf16(pfA, vfA, o[nb], 0, 0, 0);
                o[nb] = __builtin_amdgcn_mfma_f32_16x16x32_bf16(pfB, vfB, o[nb], 0, 0, 0);
            }
        }
    }
    if (s2 < ntiles) {   // odd tail: single tile s2 == tt (diagonal)
        __syncthreads();
        {   // 64 rows x 8 chunks each (2 int4/thread)
            const int sr = tid >> 2, cb = (tid & 3) * 2;
            const short* kp = kbase + (size_t)(s2 * 64 + sr) * RS;
            const short* vp = vbase + (size_t)sr * T_LEN + s2 * 64;
            #pragma unroll
            for (int u = 0; u < 2; ++u) {
                const int c = cb + u;
                *(int4*)&Ks[sr][(c ^ (sr & 7)) * 8] = *(const int4*)(kp + c * 8);
                *(int4*)&Vt[sr][(c ^ (sr & 7)) * 8] = *(const int4*)(vp + c * 8);
            }
        }
        __syncthreads();
        floatx4 sf[4];
        #pragma unroll
        for (int mb = 0; mb < 4; ++mb)
            #pragma unroll
            for (int e = 0; e < 4; ++e) sf[mb][e] = 0.f;
        #pragma unroll
        for (int ks = 0; ks < 2; ++ks) {
            const int krow = w * 16 + r;
            short8v kf = *(const short8v*)&Ks[krow][((ks * 4 + q) ^ (krow & 7)) * 8];
            #pragma unroll
            for (int mb = 0; mb < 4; ++mb)
                sf[mb] = __builtin_amdgcn_mfma_f32_16x16x32_bf16(qf[mb][ks], kf, sf[mb], 0, 0, 0);
        }
        #pragma unroll
        for (int mb = 0; mb < 4; ++mb)
            #pragma unroll
            for (int i = 0; i < 4; ++i) {
                const int rl = mb * 16 + q * 4 + i;
                float p = (w * 16 + r > rl) ? 0.f : __expf(sf[mb][i]);
                l_part[mb][i] += p;
                const int c = (w * 2 + (r >> 3)) ^ (rl & 7);
                Ps[0][rl][c * 8 + (r & 7)] = f2bf(p);
            }
        __syncthreads();
        #pragma unroll
        for (int ks = 0; ks < 2; ++ks) {
            const int prow = w * 16 + r;
            short8v pf = *(const short8v*)&Ps[0][prow][((ks * 4 + q) ^ (prow & 7)) * 8];
            #pragma unroll
            for (int nb = 0; nb < 4; ++nb) {
                const int vrow = nb * 16 + r;
                short8v vf = *(const short8v*)&Vt[vrow][(((ks * 4 + q) ^ (vrow & 7))) * 8];
                o[nb] = __builtin_amdgcn_mfma_f32_16x16x32_bf16(pf, vf, o[nb], 0, 0, 0);
            }
        }
    }

    // ---- epilogue: l reduce (16 r-lanes, then cross-wave), ctx write
    #pragma unroll
    for (int mb = 0; mb < 4; ++mb)
        #pragma unroll
        for (int i = 0; i < 4; ++i) {
            float v = l_part[mb][i];
            v += __shfl_xor(v, 1, 16);
            v += __shfl_xor(v, 2, 16);
            v += __shfl_xor(v, 4, 16);
            v += __shfl_xor(v, 8, 16);
            if (r == 0) Lred[w][mb * 16 + q * 4 + i] = v;
        }
    __syncthreads();
    if (tid < 64) {
        float s = Lred[0][tid] + Lred[1][tid] + Lred[2][tid] + Lred[3][tid];
        Lr[(size_t)bh * T_LEN + t0 + tid] = s;
        Lred[0][tid] = s;
    }
    __syncthreads();
    #pragma unroll
    for (int i = 0; i < 4; ++i) {
        const int tl = w * 16 + q * 4 + i;
        const float inv = 1.0f / Lred[0][tl];
        #pragma unroll
        for (int nb = 0; nb < 4; ++nb)
            ctx[((size_t)(t0 + tl) * BSZ + b) * EMB + h * HDIM + nb * 16 + r] =
                f2bf(o[nb][i] * inv);
    }
}

// ---------------------------------------------------------------------------
// avg_w[b,t,s] = (1/H) sum_h exp(qk) / l_h[t]. 64x64 output tiles.
// LDS-FREE main loop: for mfma_16x16x32, the A-fragment (Q row w*16+r,
// 16B at col h*64+ks*32+q*8) and B-fragment (K row nb*16+r, same col
// pattern) are CONTIGUOUS 16B chunks in the global qk layout -> each lane
// loads its fragments directly global->register (L1/L2-served; the 4x
// cross-wave K redundancy is L1 broadcast). No staging, no barriers in
// the loop, no bank conflicts. 2-deep software pipeline (named A/B sets,
// static indexing): head h+1's 10 loads issue under head h's MFMA+exp.
// ---------------------------------------------------------------------------
__global__ __launch_bounds__(256) void avg_w_k(const short* __restrict__ qk,
        const float* __restrict__ Lr, float* __restrict__ avg) {
    const int s0 = blockIdx.x * 64, t0 = blockIdx.y * 64, b = blockIdx.z;
    const int tid = threadIdx.x;
    float* outb = avg + (size_t)b * T_LEN * T_LEN;
    if (s0 > t0) {   // fully masked tile: zero-fill (d_out is poisoned)
        const int ty = tid >> 4, tx = tid & 15;
        const float4 z = make_float4(0.f, 0.f, 0.f, 0.f);
        #pragma unroll
        for (int i = 0; i < 4; ++i)
            *(float4*)&outb[(size_t)(t0 + ty * 4 + i) * T_LEN + s0 + tx * 4] = z;
        return;
    }
    __shared__ float Lbuf[NHEAD][64];
    const int lane = tid & 63, w = tid >> 6;
    const int q = lane >> 4, r = lane & 15;
    const int RS = BSZ * QK_LD;
    const bool diagblk = (s0 == t0);

    // pre-inverted denominators: 16 heads x 64 t-rows
    #pragma unroll
    for (int u = 0; u < 4; ++u) {
        const int li = tid * 4 + u;
        const int h = li >> 6, tl = li & 63;
        Lbuf[h][tl] = 0.0625f / Lr[(size_t)(b * NHEAD + h) * T_LEN + t0 + tl];
    }
    __syncthreads();

    // direct fragment base addresses
    const short* qp = qk + (size_t)b * QK_LD + (size_t)(t0 + w * 16 + r) * RS + q * 8;
    const short* kp0 = qk + (size_t)b * QK_LD + EMB + (size_t)(s0 + r) * RS + q * 8;
    const short* kp[4];
    #pragma unroll
    for (int nb = 0; nb < 4; ++nb) kp[nb] = kp0 + (size_t)(nb * 16) * RS;

    floatx4 acc[4];
    #pragma unroll
    for (int nb = 0; nb < 4; ++nb)
        #pragma unroll
        for (int e = 0; e < 4; ++e) acc[nb][e] = 0.f;

#define LOADSET(Q0, Q1, KF, hh) do {                                         \
        const int _off = (hh) * 64;                                          \
        Q0 = *(const short8v*)(qp + _off);                                   \
        Q1 = *(const short8v*)(qp + _off + 32);                              \
        _Pragma("unroll")                                                    \
        for (int _nb = 0; _nb < 4; ++_nb) {                                  \
            KF[_nb * 2]     = *(const short8v*)(kp[_nb] + _off);             \
            KF[_nb * 2 + 1] = *(const short8v*)(kp[_nb] + _off + 32);        \
        }                                                                    \
    } while (0)

#define COMPUTE(Q0, Q1, KF, hh) do {                                         \
        floatx4 sf[4];                                                       \
        _Pragma("unroll")                                                    \
        for (int _nb = 0; _nb < 4; ++_nb) {                                  \
            _Pragma("unroll")                                                \
            for (int _e = 0; _e < 4; ++_e) sf[_nb][_e] = 0.f;                \
            sf[_nb] = __builtin_amdgcn_mfma_f32_16x16x32_bf16(Q0, KF[_nb * 2],     sf[_nb], 0, 0, 0); \
            sf[_nb] = __builtin_amdgcn_mfma_f32_16x16x32_bf16(Q1, KF[_nb * 2 + 1], sf[_nb], 0, 0, 0); \
        }                                                                    \
        _Pragma("unroll")                                                    \
        for (int _i = 0; _i < 4; ++_i) {                                     \
            const int _tl = w * 16 + q * 4 + _i;                             \
            const float _inv = Lbuf[hh][_tl];                                \
            _Pragma("unroll")                                                \
            for (int _nb = 0; _nb < 4; ++_nb) {                              \
                float _e2 = (diagblk && (_nb * 16 + r > _tl))                \
                            ? 0.f : __expf(sf[_nb][_i]) * _inv;              \
                acc[_nb][_i] += _e2;                                         \
            }                                                                \
        }                                                                    \
    } while (0)

    short8v qA0, qA1, kA[8], qB0, qB1, kB[8];
    LOADSET(qA0, qA1, kA, 0);
    #pragma unroll
    for (int h = 0; h < NHEAD; h += 2) {
        LOADSET(qB0, qB1, kB, h + 1);
        COMPUTE(qA0, qA1, kA, h);
        if (h + 2 < NHEAD) LOADSET(qA0, qA1, kA, h + 2);
        COMPUTE(qB0, qB1, kB, h + 1);
    }
#undef LOADSET
#undef COMPUTE

    #pragma unroll
    for (int i = 0; i < 4; ++i) {
        const int t = t0 + w * 16 + q * 4 + i;
        #pragma unroll
        for (int nb = 0; nb < 4; ++nb)
            outb[(size_t)t * T_LEN + s0 + nb * 16 + r] = acc[nb][i];
    }
}

// ---------------------------------------------------------------------------
// Workspace (40.25 MiB, matching the proven-safe layout). query-bf16 is
// ALIASED onto ctxb: its lifetime ends at the QKV gemm, before flash_fwd
// writes ctx (stream-serial, no overlap).
// ---------------------------------------------------------------------------
extern "C" void kernel_launch(void* const* d_in, const int* in_sizes, int n_in,
                              void* d_out, int out_size, void* d_ws, size_t ws_size,
                              hipStream_t stream) {
    (void)in_sizes; (void)n_in; (void)out_size; (void)ws_size;
    const float* query = (const float*)d_in[0];
    const float* w_in  = (const float*)d_in[1];
    const float* b_in  = (const float*)d_in[2];
    const float* w_out = (const float*)d_in[3];
    const float* b_out = (const float*)d_in[4];

    float* out = (float*)d_out;                           // [T,B,E] fp32
    float* avg = out + (size_t)T_LEN * BSZ * EMB;         // [B,T,T] fp32

    short* ws     = (short*)d_ws;
    short* wb_in  = ws;                                   // w_in bf16  [3072,1024]  6 MB
    short* wb_out = wb_in  + (size_t)3072 * 1024;         // w_out bf16 [1024,1024]  2 MB
    short* qkb    = wb_out + (size_t)1024 * 1024;         // q,k bf16   [4096,2048] 16 MB
    short* vTb    = qkb    + (size_t)4096 * 2048;         // V^T bf16   [B*E, T]     8 MB
    short* ctxb   = vTb    + (size_t)BSZ * EMB * T_LEN;   // ctx bf16   [4096,1024]  8 MB
    float* Lr     = (float*)(ctxb + (size_t)4096 * 1024); // [B*H, T]              256 KB
    short* qb     = ctxb;                                 // query bf16 alias (dead before flash)

    f32_to_bf16_k<<<4096, 256, 0, stream>>>(query, qb,     4096 * 1024);
    f32_to_bf16_k<<<3072, 256, 0, stream>>>(w_in,  wb_in,  3072 * 1024);
    f32_to_bf16_k<<<1024, 256, 0, stream>>>(w_out, wb_out, 1024 * 1024);

    // QKV projection: q,k -> qkb, v -> vTb (transposed)
    // grid x=mtile (32), y=ntile (24): per-XCD A-slab residency
    gemm_bf16<<<dim3(32, 24), 256, 0, stream>>>(qb, wb_in, b_in, qkb, vTb,
                                                4096, 3072, 1024, EMB, 1, QK_LD);
    flash_fwd<<<dim3(32, 32), 256, 0, stream>>>(qkb, vTb, ctxb, Lr);
    avg_w_k<<<dim3(32, 32, 2), 256, 0, stream>>>(qkb, Lr, avg);
    gemm_bf16<<<dim3(32, 8), 256, 0, stream>>>(ctxb, wb_out, b_out, out, (short*)0,
                                               4096, 1024, 1024, 0, 0, 1024);
}

// Round 4
// 236.065 us; speedup vs baseline: 1.4355x; 1.4355x over previous
//
#include <hip/hip_runtime.h>
#include <math.h>

#define T_LEN 2048
#define BSZ 2
#define EMB 1024
#define NHEAD 16
#define HDIM 64
#define QK_LD 2048   // q,k packed [T*B, 2E]

typedef __attribute__((ext_vector_type(8))) short short8v;   // 8 bf16 (4 VGPRs)
typedef __attribute__((ext_vector_type(4))) float floatx4;   // MFMA C/D

__device__ __forceinline__ short f2bf(float f) {
    unsigned u = __float_as_uint(f);
    u += 0x7fffu + ((u >> 16) & 1u);   // RNE
    return (short)(u >> 16);
}

// async global->LDS, 16B per lane; LDS dest is wave-uniform base + lane*16.
__device__ __forceinline__ void async16(const short* g, short* l) {
    __builtin_amdgcn_global_load_lds(
        (const __attribute__((address_space(1))) void*)g,
        (__attribute__((address_space(3))) void*)l, 16, 0, 0);
}

// ---------------------------------------------------------------------------
__global__ __launch_bounds__(256) void f32_to_bf16_k(const float* __restrict__ src,
                                                     short* __restrict__ dst, int n) {
    int i = (blockIdx.x * 256 + threadIdx.x) * 4;
    if (i >= n) return;
    float4 v = *(const float4*)(src + i);
    short4 o = make_short4(f2bf(v.x), f2bf(v.y), f2bf(v.z), f2bf(v.w));
    *(short4*)(dst + i) = o;
}

// ---------------------------------------------------------------------------
// C = A[M,K]*B[N,K]^T + bias; cols < scale_cols get *0.125 (q scale).
// bf16 MFMA 16x16x32, 128x128 tile, BK=32, 4 waves.
// Staging: __builtin_amdgcn_global_load_lds width 16 (m97 structure).
//   LDS dest is LINEAR (wave-uniform base + lane*16); the read-side XOR
//   swizzle (chunk q ^ ((row>>1)&3), 2-way-free banks) is an involution,
//   so it is applied to the GLOBAL source chunk index instead (rule 21:
//   linear dest + inverse-swizzled source + swizzled read).
// GRID IS (mtile, ntile): linear%8 = mtile%8, so each XCD keeps its 4
// A-slabs resident in L2. If vTout != 0, cols >= 2*EMB are written
// TRANSPOSED to vT[b][e][t].
// ---------------------------------------------------------------------------
__global__ __launch_bounds__(256) void gemm_bf16(const short* __restrict__ A,
        const short* __restrict__ B, const float* __restrict__ bias,
        void* __restrict__ Cout, short* __restrict__ vTout,
        int M, int N, int K, int scale_cols, int out_bf16, int ldC) {
    __shared__ short As[128][32];
    __shared__ short Bs[128][32];
    const int tid = threadIdx.x;
    const int m0 = blockIdx.x * 128, n0 = blockIdx.y * 128;   // x=mtile (XCD locality)
    const int lane = tid & 63, w = tid >> 6;
    const int q = lane >> 4, r = lane & 15;
    const int wr = w >> 1, wc = w & 1;

    // Staging geometry: wave w stages 16-row chunks {w, w+4} of both tiles.
    // Lane l -> row chunk*16 + (l>>2), 16B position (l&3) within the 64B row.
    const int srow = lane >> 2;                  // 0..15 within chunk
    const int spos = lane & 3;                   // 16B slot within row
    const int rowL = w * 16 + srow;              // chunk w   (rows 0..63)
    const int rowH = 64 + rowL;                  // chunk w+4 (rows 64..127)
    const int csrc = spos ^ ((rowL >> 1) & 3);   // f(rowH) == f(rowL)
    const short* gA0 = A + (size_t)(m0 + rowL) * K + csrc * 8;
    const short* gA1 = A + (size_t)(m0 + rowH) * K + csrc * 8;
    const short* gB0 = B + (size_t)(n0 + rowL) * K + csrc * 8;
    const short* gB1 = B + (size_t)(n0 + rowH) * K + csrc * 8;
    short* lA0 = &As[w * 16][0];                 // wave-uniform LDS bases
    short* lA1 = &As[64 + w * 16][0];
    short* lB0 = &Bs[w * 16][0];
    short* lB1 = &Bs[64 + w * 16][0];

    floatx4 acc[4][4];
    #pragma unroll
    for (int a = 0; a < 4; ++a)
        #pragma unroll
        for (int b2 = 0; b2 < 4; ++b2)
            #pragma unroll
            for (int e = 0; e < 4; ++e) acc[a][b2][e] = 0.f;

    for (int k0 = 0; k0 < K; k0 += 32) {
        __syncthreads();                 // previous iter's ds_reads complete
        async16(gA0 + k0, lA0);
        async16(gA1 + k0, lA1);
        async16(gB0 + k0, lB0);
        async16(gB1 + k0, lB1);
        __syncthreads();                 // vmcnt(0) drain + barrier
        short8v af[4], bfr[4];
        #pragma unroll
        for (int mb = 0; mb < 4; ++mb) {
            int row = wr * 64 + mb * 16 + r;
            af[mb] = *(const short8v*)&As[row][(q ^ ((row >> 1) & 3)) * 8];
        }
        #pragma unroll
        for (int nb = 0; nb < 4; ++nb) {
            int row = wc * 64 + nb * 16 + r;
            bfr[nb] = *(const short8v*)&Bs[row][(q ^ ((row >> 1) & 3)) * 8];
        }
        #pragma unroll
        for (int mb = 0; mb < 4; ++mb)
            #pragma unroll
            for (int nb = 0; nb < 4; ++nb)
                acc[mb][nb] = __builtin_amdgcn_mfma_f32_16x16x32_bf16(af[mb], bfr[nb], acc[mb][nb], 0, 0, 0);
    }

    #pragma unroll
    for (int nb = 0; nb < 4; ++nb) {
        const int col = n0 + wc * 64 + nb * 16 + r;
        const float bi = bias[col];
        const float sc = (col < scale_cols) ? 0.125f : 1.0f;
        if (vTout && col >= 2 * EMB) {
            const int e = col - 2 * EMB;
            #pragma unroll
            for (int mb = 0; mb < 4; ++mb) {
                const int base = m0 + wr * 64 + mb * 16 + q * 4;   // multiple of 4
                float v0 = acc[mb][nb][0] + bi, v1 = acc[mb][nb][1] + bi;
                float v2 = acc[mb][nb][2] + bi, v3 = acc[mb][nb][3] + bi;
                // rows (t*2+b): i=0,2 -> b=0 t,t+1 ; i=1,3 -> b=1 t,t+1
                unsigned lo = (unsigned short)f2bf(v0) | ((unsigned)(unsigned short)f2bf(v2) << 16);
                unsigned hi = (unsigned short)f2bf(v1) | ((unsigned)(unsigned short)f2bf(v3) << 16);
                *(unsigned*)&vTout[(size_t)e * T_LEN + (base >> 1)]         = lo;
                *(unsigned*)&vTout[((size_t)EMB + e) * T_LEN + (base >> 1)] = hi;
            }
        } else {
            #pragma unroll
            for (int mb = 0; mb < 4; ++mb)
                #pragma unroll
                for (int i = 0; i < 4; ++i) {
                    const int rowg = m0 + wr * 64 + mb * 16 + q * 4 + i;
                    const float v = (acc[mb][nb][i] + bi) * sc;
                    if (out_bf16) ((short*)Cout)[(size_t)rowg * ldC + col] = f2bf(v);
                    else          ((float*)Cout)[(size_t)rowg * ldC + col] = v;
                }
        }
    }
}

// ---------------------------------------------------------------------------
// Flash causal attention. ONE t-tile per block (grid 32 bh x 32 tt), big
// tiles dispatched first (tt = 31 - blockIdx.y) so the tail is short work.
// linear%8 = bh%8 -> each XCD hosts 4 bh values, K/V working set 2 MB fits
// per-XCD L2. 2 s-tiles per staging round via global_load_lds width 16
// (linear LDS dest + inverse-swizzled global source; read swizzle is the
// same involution). P double-buffered, no online max.
// ---------------------------------------------------------------------------
__global__ __launch_bounds__(256) void flash_fwd(const short* __restrict__ qk,
        const short* __restrict__ vT, short* __restrict__ ctx,
        float* __restrict__ Lr) {
    __shared__ short Ks[128][64];       // 2 s-tiles of K
    __shared__ short Vt[64][128];       // V^T: [d][2 s-tiles]
    __shared__ short Ps[2][64][64];     // P dbuf; Ps[0] doubles as Q staging
    __shared__ float Lred[4][64];
    const int tid = threadIdx.x;
    const int bh = blockIdx.x;          // XCD locality: linear%8 = bh%8
    const int tt = 31 - blockIdx.y;     // big tiles first
    const int t0 = tt << 6;
    const int b = bh >> 4, h = bh & 15;
    const int lane = tid & 63, w = tid >> 6;
    const int q = lane >> 4, r = lane & 15;
    const int RS = BSZ * QK_LD;

    const short* qbase = qk + (size_t)b * QK_LD + h * HDIM;
    const short* kbase = qbase + EMB;
    const short* vbase = vT + ((size_t)b * EMB + h * HDIM) * T_LEN;

    // async staging geometry (paired rounds):
    // K: Ks[128][64]. issue (w,j): rows w*32+j*8; lane -> row +(l>>3), chunk l&7.
    //    j*8 doesn't change row&7 -> source chunk swizzle is j-invariant.
    const int krow0 = w * 32 + (lane >> 3);
    const short* kg = kbase + (size_t)krow0 * RS + ((lane & 7) ^ (krow0 & 7)) * 8;
    // V: Vt[64][128]. issue (w,j): rows w*16+j*4; lane -> row +(l>>4), chunk l&15.
    const int vrow0 = w * 16 + (lane >> 4);
    const short* vg[4];
    #pragma unroll
    for (int j = 0; j < 4; ++j) {
        const int vr = vrow0 + j * 4;
        const int gc = ((lane & 15) & 8) | (((lane & 15) & 7) ^ (vr & 7));
        vg[j] = vbase + (size_t)vr * T_LEN + gc * 8;
    }

    {   // stage Q into Ps[0]
        const int sr = tid >> 3, c8 = tid & 7;
        *(int4*)&Ps[0][sr][(c8 ^ (sr & 7)) * 8] =
            *(const int4*)(qbase + (size_t)(t0 + sr) * RS + c8 * 8);
        *(int4*)&Ps[0][sr + 32][(c8 ^ ((sr + 32) & 7)) * 8] =
            *(const int4*)(qbase + (size_t)(t0 + sr + 32) * RS + c8 * 8);
    }
    __syncthreads();
    short8v qf[4][2];
    #pragma unroll
    for (int mb = 0; mb < 4; ++mb)
        #pragma unroll
        for (int ks = 0; ks < 2; ++ks) {
            int row = mb * 16 + r;
            qf[mb][ks] = *(const short8v*)&Ps[0][row][((ks * 4 + q) ^ (row & 7)) * 8];
        }

    float l_part[4][4];
    floatx4 o[4];
    #pragma unroll
    for (int mb = 0; mb < 4; ++mb)
        #pragma unroll
        for (int i = 0; i < 4; ++i) l_part[mb][i] = 0.f;
    #pragma unroll
    for (int nb = 0; nb < 4; ++nb)
        #pragma unroll
        for (int e = 0; e < 4; ++e) o[nb][e] = 0.f;

    const int ntiles = tt + 1;
    int s2 = 0;
    for (; s2 + 2 <= ntiles; s2 += 2) {   // paired rounds: 128 s per stage
        __syncthreads();                  // prior PV reads of Ks/Vt done
        {   // async K: 4 issues x 8 rows; V: 4 issues x 4 rows
            const short* kgr = kg + (size_t)(s2 * 64) * RS;
            #pragma unroll
            for (int j = 0; j < 4; ++j)
                async16(kgr + (size_t)(j * 8) * RS, &Ks[w * 32 + j * 8][0]);
            #pragma unroll
            for (int j = 0; j < 4; ++j)
                async16(vg[j] + s2 * 64, &Vt[w * 16 + j * 4][0]);
        }
        __syncthreads();                  // vmcnt(0) drain + barrier
        #pragma unroll
        for (int t2 = 0; t2 < 2; ++t2) {   // QK + P for both tiles
            floatx4 sf[4];
            #pragma unroll
            for (int mb = 0; mb < 4; ++mb)
                #pragma unroll
                for (int e = 0; e < 4; ++e) sf[mb][e] = 0.f;
            #pragma unroll
            for (int ks = 0; ks < 2; ++ks) {
                const int krow = t2 * 64 + w * 16 + r;
                short8v kf = *(const short8v*)&Ks[krow][((ks * 4 + q) ^ (krow & 7)) * 8];
                #pragma unroll
                for (int mb = 0; mb < 4; ++mb)
                    sf[mb] = __builtin_amdgcn_mfma_f32_16x16x32_bf16(qf[mb][ks], kf, sf[mb], 0, 0, 0);
            }
            const bool diag = (s2 + t2 == tt);
            #pragma unroll
            for (int mb = 0; mb < 4; ++mb)
                #pragma unroll
                for (int i = 0; i < 4; ++i) {
                    const int rl = mb * 16 + q * 4 + i;
                    float p = (diag && (w * 16 + r > rl)) ? 0.f : __expf(sf[mb][i]);
                    l_part[mb][i] += p;
                    const int c = (w * 2 + (r >> 3)) ^ (rl & 7);
                    Ps[t2][rl][c * 8 + (r & 7)] = f2bf(p);
                }
        }
        __syncthreads();
        #pragma unroll
        for (int ks = 0; ks < 2; ++ks) {   // PV both s-halves
            const int prow = w * 16 + r;
            const int pcp = ((ks * 4 + q) ^ (prow & 7)) * 8;
            short8v pfA = *(const short8v*)&Ps[0][prow][pcp];
            short8v pfB = *(const short8v*)&Ps[1][prow][pcp];
            #pragma unroll
            for (int nb = 0; nb < 4; ++nb) {
                const int vrow = nb * 16 + r;
                const int pcv = (ks * 4 + q) ^ (vrow & 7);
                short8v vfA = *(const short8v*)&Vt[vrow][pcv * 8];
                short8v vfB = *(const short8v*)&Vt[vrow][(8 | pcv) * 8];
                o[nb] = __builtin_amdgcn_mfma_f32_16x16x32_bf16(pfA, vfA, o[nb], 0, 0, 0);
                o[nb] = __builtin_amdgcn_mfma_f32_16x16x32_bf16(pfB, vfB, o[nb], 0, 0, 0);
            }
        }
    }
    if (s2 < ntiles) {   // odd tail: single tile s2 == tt (diagonal)
        __syncthreads();
        {   // 64 rows x 8 chunks each (2 int4/thread)
            const int sr = tid >> 2, cb = (tid & 3) * 2;
            const short* kp = kbase + (size_t)(s2 * 64 + sr) * RS;
            const short* vp = vbase + (size_t)sr * T_LEN + s2 * 64;
            #pragma unroll
            for (int u = 0; u < 2; ++u) {
                const int c = cb + u;
                *(int4*)&Ks[sr][(c ^ (sr & 7)) * 8] = *(const int4*)(kp + c * 8);
                *(int4*)&Vt[sr][(c ^ (sr & 7)) * 8] = *(const int4*)(vp + c * 8);
            }
        }
        __syncthreads();
        floatx4 sf[4];
        #pragma unroll
        for (int mb = 0; mb < 4; ++mb)
            #pragma unroll
            for (int e = 0; e < 4; ++e) sf[mb][e] = 0.f;
        #pragma unroll
        for (int ks = 0; ks < 2; ++ks) {
            const int krow = w * 16 + r;
            short8v kf = *(const short8v*)&Ks[krow][((ks * 4 + q) ^ (krow & 7)) * 8];
            #pragma unroll
            for (int mb = 0; mb < 4; ++mb)
                sf[mb] = __builtin_amdgcn_mfma_f32_16x16x32_bf16(qf[mb][ks], kf, sf[mb], 0, 0, 0);
        }
        #pragma unroll
        for (int mb = 0; mb < 4; ++mb)
            #pragma unroll
            for (int i = 0; i < 4; ++i) {
                const int rl = mb * 16 + q * 4 + i;
                float p = (w * 16 + r > rl) ? 0.f : __expf(sf[mb][i]);
                l_part[mb][i] += p;
                const int c = (w * 2 + (r >> 3)) ^ (rl & 7);
                Ps[0][rl][c * 8 + (r & 7)] = f2bf(p);
            }
        __syncthreads();
        #pragma unroll
        for (int ks = 0; ks < 2; ++ks) {
            const int prow = w * 16 + r;
            short8v pf = *(const short8v*)&Ps[0][prow][((ks * 4 + q) ^ (prow & 7)) * 8];
            #pragma unroll
            for (int nb = 0; nb < 4; ++nb) {
                const int vrow = nb * 16 + r;
                short8v vf = *(const short8v*)&Vt[vrow][(((ks * 4 + q) ^ (vrow & 7))) * 8];
                o[nb] = __builtin_amdgcn_mfma_f32_16x16x32_bf16(pf, vf, o[nb], 0, 0, 0);
            }
        }
    }

    // ---- epilogue: l reduce (16 r-lanes, then cross-wave), ctx write
    #pragma unroll
    for (int mb = 0; mb < 4; ++mb)
        #pragma unroll
        for (int i = 0; i < 4; ++i) {
            float v = l_part[mb][i];
            v += __shfl_xor(v, 1, 16);
            v += __shfl_xor(v, 2, 16);
            v += __shfl_xor(v, 4, 16);
            v += __shfl_xor(v, 8, 16);
            if (r == 0) Lred[w][mb * 16 + q * 4 + i] = v;
        }
    __syncthreads();
    if (tid < 64) {
        float s = Lred[0][tid] + Lred[1][tid] + Lred[2][tid] + Lred[3][tid];
        Lr[(size_t)bh * T_LEN + t0 + tid] = s;
        Lred[0][tid] = s;
    }
    __syncthreads();
    #pragma unroll
    for (int i = 0; i < 4; ++i) {
        const int tl = w * 16 + q * 4 + i;
        const float inv = 1.0f / Lred[0][tl];
        #pragma unroll
        for (int nb = 0; nb < 4; ++nb)
            ctx[((size_t)(t0 + tl) * BSZ + b) * EMB + h * HDIM + nb * 16 + r] =
                f2bf(o[nb][i] * inv);
    }
}

// ---------------------------------------------------------------------------
// avg_w[b,t,s] = (1/H) sum_h exp(qk) / l_h[t]. 64x64 output tiles, 2 heads
// per staging round (R2 structure), staging via global_load_lds width 16:
// LDS dest linear (wave-uniform base + lane*16), global source chunk
// inverse-swizzled gc=(c&8)|((c&7)^(row&7)) (involution), read side
// byte-identical to the verified reg-staged version. No staging VALU,
// no staging bank conflicts.
// ---------------------------------------------------------------------------
__global__ __launch_bounds__(256) void avg_w_k(const short* __restrict__ qk,
        const float* __restrict__ Lr, float* __restrict__ avg) {
    const int s0 = blockIdx.x * 64, t0 = blockIdx.y * 64, b = blockIdx.z;
    const int tid = threadIdx.x;
    float* outb = avg + (size_t)b * T_LEN * T_LEN;
    if (s0 > t0) {   // fully masked tile: zero-fill (d_out is poisoned)
        const int ty = tid >> 4, tx = tid & 15;
        const float4 z = make_float4(0.f, 0.f, 0.f, 0.f);
        #pragma unroll
        for (int i = 0; i < 4; ++i)
            *(float4*)&outb[(size_t)(t0 + ty * 4 + i) * T_LEN + s0 + tx * 4] = z;
        return;
    }
    __shared__ short Qs[64][128];
    __shared__ short Ks[64][128];
    __shared__ float Lbuf[NHEAD][64];
    const int lane = tid & 63, w = tid >> 6;
    const int q = lane >> 4, r = lane & 15;
    const short* qbase = qk + (size_t)b * QK_LD;
    const int RS = BSZ * QK_LD;

    // pre-inverted denominators: 16 heads x 64 t-rows (published by drain barrier)
    #pragma unroll
    for (int u = 0; u < 4; ++u) {
        const int li = tid * 4 + u;
        const int h = li >> 6, tl = li & 63;
        Lbuf[h][tl] = 0.0625f / Lr[(size_t)(b * NHEAD + h) * T_LEN + t0 + tl];
    }

    // async staging geometry: wave w stages rows [w*16, w*16+16) of Qs and Ks
    // via 4 issues of 4 rows each; lane -> row +(l>>4), LDS chunk l&15.
    // global source chunk = (c&8)|((c&7)^(row&7))  (involution of read swizzle)
    const short* qg[4]; const short* kg[4];
    #pragma unroll
    for (int j = 0; j < 4; ++j) {
        const int row = w * 16 + j * 4 + (lane >> 4);
        const int c = lane & 15;
        const int gc = (c & 8) | ((c & 7) ^ (row & 7));
        qg[j] = qbase + (size_t)(t0 + row) * RS + gc * 8;
        kg[j] = qbase + EMB + (size_t)(s0 + row) * RS + gc * 8;
    }

    floatx4 acc[4];
    #pragma unroll
    for (int nb = 0; nb < 4; ++nb)
        #pragma unroll
        for (int e = 0; e < 4; ++e) acc[nb][e] = 0.f;

    for (int hp = 0; hp < 8; ++hp) {       // head pairs; hp offset = hp*128 shorts
        __syncthreads();                   // prior round's fragment reads done
        #pragma unroll
        for (int j = 0; j < 4; ++j)
            async16(qg[j] + hp * 128, &Qs[w * 16 + j * 4][0]);
        #pragma unroll
        for (int j = 0; j < 4; ++j)
            async16(kg[j] + hp * 128, &Ks[w * 16 + j * 4][0]);
        __syncthreads();                   // vmcnt(0) drain + barrier

        #pragma unroll
        for (int hs = 0; hs < 2; ++hs) {
            const int h = hp * 2 + hs;
            floatx4 sf[4];
            #pragma unroll
            for (int nb = 0; nb < 4; ++nb)
                #pragma unroll
                for (int e = 0; e < 4; ++e) sf[nb][e] = 0.f;
            #pragma unroll
            for (int ks = 0; ks < 2; ++ks) {
                const int qrow = w * 16 + r;
                short8v qfr = *(const short8v*)
                    &Qs[qrow][((hs * 8) | ((ks * 4 + q) ^ (qrow & 7))) * 8];
                #pragma unroll
                for (int nb = 0; nb < 4; ++nb) {
                    const int krow = nb * 16 + r;
                    short8v kfr = *(const short8v*)
                        &Ks[krow][((hs * 8) | ((ks * 4 + q) ^ (krow & 7))) * 8];
                    sf[nb] = __builtin_amdgcn_mfma_f32_16x16x32_bf16(qfr, kfr, sf[nb], 0, 0, 0);
                }
            }
            #pragma unroll
            for (int i = 0; i < 4; ++i) {
                const int tl = w * 16 + q * 4 + i;
                const float inv = Lbuf[h][tl];
                #pragma unroll
                for (int nb = 0; nb < 4; ++nb) {
                    float e = (s0 == t0 && (nb * 16 + r > tl))
                              ? 0.f : __expf(sf[nb][i]) * inv;
                    acc[nb][i] += e;
                }
            }
        }
    }

    #pragma unroll
    for (int i = 0; i < 4; ++i) {
        const int t = t0 + w * 16 + q * 4 + i;
        #pragma unroll
        for (int nb = 0; nb < 4; ++nb)
            outb[(size_t)t * T_LEN + s0 + nb * 16 + r] = acc[nb][i];
    }
}

// ---------------------------------------------------------------------------
// Workspace (40.25 MiB, matching the proven-safe layout). query-bf16 is
// ALIASED onto ctxb: its lifetime ends at the QKV gemm, before flash_fwd
// writes ctx (stream-serial, no overlap).
// ---------------------------------------------------------------------------
extern "C" void kernel_launch(void* const* d_in, const int* in_sizes, int n_in,
                              void* d_out, int out_size, void* d_ws, size_t ws_size,
                              hipStream_t stream) {
    (void)in_sizes; (void)n_in; (void)out_size; (void)ws_size;
    const float* query = (const float*)d_in[0];
    const float* w_in  = (const float*)d_in[1];
    const float* b_in  = (const float*)d_in[2];
    const float* w_out = (const float*)d_in[3];
    const float* b_out = (const float*)d_in[4];

    float* out = (float*)d_out;                           // [T,B,E] fp32
    float* avg = out + (size_t)T_LEN * BSZ * EMB;         // [B,T,T] fp32

    short* ws     = (short*)d_ws;
    short* wb_in  = ws;                                   // w_in bf16  [3072,1024]  6 MB
    short* wb_out = wb_in  + (size_t)3072 * 1024;         // w_out bf16 [1024,1024]  2 MB
    short* qkb    = wb_out + (size_t)1024 * 1024;         // q,k bf16   [4096,2048] 16 MB
    short* vTb    = qkb    + (size_t)4096 * 2048;         // V^T bf16   [B*E, T]     8 MB
    short* ctxb   = vTb    + (size_t)BSZ * EMB * T_LEN;   // ctx bf16   [4096,1024]  8 MB
    float* Lr     = (float*)(ctxb + (size_t)4096 * 1024); // [B*H, T]              256 KB
    short* qb     = ctxb;                                 // query bf16 alias (dead before flash)

    f32_to_bf16_k<<<4096, 256, 0, stream>>>(query, qb,     4096 * 1024);
    f32_to_bf16_k<<<3072, 256, 0, stream>>>(w_in,  wb_in,  3072 * 1024);
    f32_to_bf16_k<<<1024, 256, 0, stream>>>(w_out, wb_out, 1024 * 1024);

    // QKV projection: q,k -> qkb, v -> vTb (transposed)
    // grid x=mtile (32), y=ntile (24): per-XCD A-slab residency
    gemm_bf16<<<dim3(32, 24), 256, 0, stream>>>(qb, wb_in, b_in, qkb, vTb,
                                                4096, 3072, 1024, EMB, 1, QK_LD);
    flash_fwd<<<dim3(32, 32), 256, 0, stream>>>(qkb, vTb, ctxb, Lr);
    avg_w_k<<<dim3(32, 32, 2), 256, 0, stream>>>(qkb, Lr, avg);
    gemm_bf16<<<dim3(32, 8), 256, 0, stream>>>(ctxb, wb_out, b_out, out, (short*)0,
                                               4096, 1024, 1024, 0, 0, 1024);
}